// Round 2
// baseline (223.611 us; speedup 1.0000x reference)
//
#include <hip/hip_runtime.h>
#include <hip/hip_bf16.h>

// ProbsNet: out = mean over 5 of [p_m @ tmp_{0 or 1}]
//   tmp_t[i] = sum_d sigmoid(pB*(pBEV*BEV + ST_t[i,d])) * W_t[i,d]
//   p_m = 84-entry softmax expansion of probs_m (4 logits)
// Memory-bound: 176 MB fp32 streamed (≈88 MB HBM + ≈88 MB L3-resident).
// R1 was latency-bound (VGPR=24, 2 loads in flight, 5.25 blocks/CU).
// R2: 21 blocks/CU exact balance + 8 loads in flight per wave.

#define D_DIM   131072
#define N_ROWS  84
#define CHUNKS  32
#define CHUNK   (D_DIM / CHUNKS)   // 4096 floats per block

// entry t of calc_probs(logits): i=t/21; r=t%21
//   r==0 -> p_i ; else r-=1, j=r/5, s=r%5: s==0 -> p_i*p_j else p_i*p_j*p_{s-1}
__device__ inline float prob_entry(const float* __restrict__ logits, int t) {
    float l0 = logits[0], l1 = logits[1], l2 = logits[2], l3 = logits[3];
    float m  = fmaxf(fmaxf(l0, l1), fmaxf(l2, l3));
    float e0 = __expf(l0 - m), e1 = __expf(l1 - m);
    float e2 = __expf(l2 - m), e3 = __expf(l3 - m);
    float inv = 1.0f / (e0 + e1 + e2 + e3);
    float p[4] = {e0 * inv, e1 * inv, e2 * inv, e3 * inv};
    int i = t / 21;
    int r = t - i * 21;
    if (r == 0) return p[i];
    r -= 1;
    int j = r / 5;
    int s = r - j * 5;
    float v = p[i] * p[j];
    return (s == 0) ? v : v * p[s - 1];
}

__global__ __launch_bounds__(256) void probsnet_kernel(
    const float* __restrict__ BEV,
    const float* __restrict__ ST0, const float* __restrict__ W0,
    const float* __restrict__ ST1, const float* __restrict__ W1,
    const float* __restrict__ probs0, const float* __restrict__ probs1,
    const float* __restrict__ probs2, const float* __restrict__ probs3,
    const float* __restrict__ probs4,
    const float* __restrict__ pBEV, const float* __restrict__ pB,
    float* __restrict__ out)
{
    const int bid    = blockIdx.x;
    const int tensor = bid / (N_ROWS * CHUNKS);          // 0 or 1
    const int rem    = bid - tensor * (N_ROWS * CHUNKS);
    const int row    = rem / CHUNKS;
    const int chunk  = rem - row * CHUNKS;

    const float bev = pBEV[0] * BEV[0];
    const float pb  = pB[0];

    const size_t base = (size_t)row * D_DIM + (size_t)chunk * CHUNK;
    const float* __restrict__ st = (tensor == 0 ? ST0 : ST1) + base;
    const float* __restrict__ wp = (tensor == 0 ? W0  : W1 ) + base;

    const int t = threadIdx.x;

    // Issue ALL 8 float4 loads before any compute: 8 outstanding 16B loads
    // per lane (8 KB/wave in flight) hides the ~200-900 cyc L2/HBM latency.
    float4 s[4], w[4];
    #pragma unroll
    for (int j = 0; j < 4; ++j) {
        const int idx = (j * 256 + t) * 4;      // coalesced, 4096-float chunk
        s[j] = *(const float4*)(st + idx);
    }
    #pragma unroll
    for (int j = 0; j < 4; ++j) {
        const int idx = (j * 256 + t) * 4;
        w[j] = *(const float4*)(wp + idx);
    }

    float acc = 0.0f;
    #pragma unroll
    for (int j = 0; j < 4; ++j) {
        float sg;
        sg = 1.0f / (1.0f + __expf(-pb * (bev + s[j].x))); acc += sg * w[j].x;
        sg = 1.0f / (1.0f + __expf(-pb * (bev + s[j].y))); acc += sg * w[j].y;
        sg = 1.0f / (1.0f + __expf(-pb * (bev + s[j].z))); acc += sg * w[j].z;
        sg = 1.0f / (1.0f + __expf(-pb * (bev + s[j].w))); acc += sg * w[j].w;
    }

    // wave64 shuffle reduction
    #pragma unroll
    for (int off = 32; off > 0; off >>= 1)
        acc += __shfl_down(acc, off, 64);

    __shared__ float red[4];
    const int wave = threadIdx.x >> 6;
    const int lane = threadIdx.x & 63;
    if (lane == 0) red[wave] = acc;
    __syncthreads();

    if (threadIdx.x == 0) {
        float bs = red[0] + red[1] + red[2] + red[3];
        float pw;
        if (tensor == 0) {
            pw = prob_entry(probs0, row);
        } else {
            pw = prob_entry(probs1, row) + prob_entry(probs2, row)
               + prob_entry(probs3, row) + prob_entry(probs4, row);
        }
        atomicAdd(out, bs * pw * 0.2f);
    }
}

extern "C" void kernel_launch(void* const* d_in, const int* in_sizes, int n_in,
                              void* d_out, int out_size, void* d_ws, size_t ws_size,
                              hipStream_t stream) {
    // setup_inputs order:
    // 0=BEV(1) 1=ST0 2=Weight0 3=ST1 4=Weight1 5=Problem(int,unused)
    // 6..10=probs0..probs4(4) 11=pBEV(1) 12=pB(1)
    const float* BEV    = (const float*)d_in[0];
    const float* ST0    = (const float*)d_in[1];
    const float* W0     = (const float*)d_in[2];
    const float* ST1    = (const float*)d_in[3];
    const float* W1     = (const float*)d_in[4];
    const float* probs0 = (const float*)d_in[6];
    const float* probs1 = (const float*)d_in[7];
    const float* probs2 = (const float*)d_in[8];
    const float* probs3 = (const float*)d_in[9];
    const float* probs4 = (const float*)d_in[10];
    const float* pBEV   = (const float*)d_in[11];
    const float* pB     = (const float*)d_in[12];
    float* out = (float*)d_out;

    // d_out is re-poisoned to 0xAA before every timed launch — zero it first.
    hipMemsetAsync(out, 0, sizeof(float), stream);

    const int grid = 2 * N_ROWS * CHUNKS;  // 5376 blocks = 21.0 blocks/CU
    probsnet_kernel<<<grid, 256, 0, stream>>>(
        BEV, ST0, W0, ST1, W1,
        probs0, probs1, probs2, probs3, probs4,
        pBEV, pB, out);
}

// Round 3
// 202.386 us; speedup vs baseline: 1.1049x; 1.1049x over previous
//
#include <hip/hip_runtime.h>
#include <hip/hip_bf16.h>

// ProbsNet: out = mean over 5 of [p_m @ tmp_{0 or 1}]
//   tmp_t[i] = sum_d sigmoid(pB*(pBEV*BEV + ST_t[i,d])) * W_t[i,d]
// R1/R2 post-mortem: single-address atomicAdd funnel cost ~50-70 us
// (1344 RMWs x ~130cyc serialized ~ 73 us = R1's entire kernel time).
// R3: two-stage reduction via d_ws partials + depth-4 register pipeline.

#define D_DIM      131072
#define N_ROWS     84
#define ROW_F4     (D_DIM / 4)            // 32768 float4 per row
#define TENSOR_F4  (N_ROWS * ROW_F4)      // 2752512 float4 per tensor
#define BLOCKS     1792                   // exactly 7 blocks/CU on 256 CUs
#define T0_BLOCKS  896                    // TENSOR_F4 / F4_PER_BLOCK (exact)
#define F4_PER_BLOCK 3072                 // 2*TENSOR_F4 / BLOCKS
#define F4_PER_THREAD 12                  // F4_PER_BLOCK / 256

// entry t of calc_probs(logits): i=t/21; r=t%21
//   r==0 -> p_i ; else r-=1, j=r/5, s=r%5: s==0 -> p_i*p_j else p_i*p_j*p_{s-1}
__device__ inline float prob_entry(const float* __restrict__ logits, int t) {
    float l0 = logits[0], l1 = logits[1], l2 = logits[2], l3 = logits[3];
    float m  = fmaxf(fmaxf(l0, l1), fmaxf(l2, l3));
    float e0 = __expf(l0 - m), e1 = __expf(l1 - m);
    float e2 = __expf(l2 - m), e3 = __expf(l3 - m);
    float inv = 1.0f / (e0 + e1 + e2 + e3);
    float p[4] = {e0 * inv, e1 * inv, e2 * inv, e3 * inv};
    int i = t / 21;
    int r = t - i * 21;
    if (r == 0) return p[i];
    r -= 1;
    int j = r / 5;
    int s = r - j * 5;
    float v = p[i] * p[j];
    return (s == 0) ? v : v * p[s - 1];
}

__global__ __launch_bounds__(256, 4) void probsnet_main(
    const float* __restrict__ BEV,
    const float* __restrict__ ST0, const float* __restrict__ W0,
    const float* __restrict__ ST1, const float* __restrict__ W1,
    const float* __restrict__ probs0, const float* __restrict__ probs1,
    const float* __restrict__ probs2, const float* __restrict__ probs3,
    const float* __restrict__ probs4,
    const float* __restrict__ pBEV, const float* __restrict__ pB,
    float* __restrict__ partials)
{
    const int bid    = blockIdx.x;
    const int t      = threadIdx.x;
    const int tensor = (bid >= T0_BLOCKS) ? 1 : 0;
    const int fb     = bid * F4_PER_BLOCK - tensor * TENSOR_F4;  // f4 base in tensor

    const float bev = pBEV[0] * BEV[0];
    const float pb  = pB[0];

    // Per-row softmax-expansion weights staged in LDS (84 rows of this tensor).
    __shared__ float wrow[N_ROWS];
    if (t < N_ROWS) {
        wrow[t] = (tensor == 0)
            ? prob_entry(probs0, t)
            : prob_entry(probs1, t) + prob_entry(probs2, t)
            + prob_entry(probs3, t) + prob_entry(probs4, t);
    }
    __syncthreads();

    const float4* __restrict__ stp =
        (const float4*)(tensor ? ST1 : ST0) + fb + t;
    const float4* __restrict__ wpp =
        (const float4*)(tensor ? W1 : W0) + fb + t;

    // Depth-4 rolling register pipeline: 8 x 16B loads in flight per lane.
    float4 sb[4], wb[4];
    #pragma unroll
    for (int k = 0; k < 4; ++k) {
        sb[k] = stp[k * 256];
        wb[k] = wpp[k * 256];
    }

    float acc = 0.0f;
    #pragma unroll
    for (int k = 0; k < F4_PER_THREAD; ++k) {
        float4 s4 = sb[k & 3];
        float4 w4 = wb[k & 3];
        if (k + 4 < F4_PER_THREAD) {
            sb[k & 3] = stp[(k + 4) * 256];
            wb[k & 3] = wpp[(k + 4) * 256];
        }
        float sum;
        sum  = w4.x / (1.0f + __expf(-pb * (bev + s4.x)));
        sum += w4.y / (1.0f + __expf(-pb * (bev + s4.y)));
        sum += w4.z / (1.0f + __expf(-pb * (bev + s4.z)));
        sum += w4.w / (1.0f + __expf(-pb * (bev + s4.w)));
        const int row = (fb + t + k * 256) >> 15;   // f4_idx / 32768
        acc = fmaf(wrow[row], sum, acc);
    }

    // wave64 shuffle reduction
    #pragma unroll
    for (int off = 32; off > 0; off >>= 1)
        acc += __shfl_down(acc, off, 64);

    __shared__ float red[4];
    const int wave = t >> 6;
    const int lane = t & 63;
    if (lane == 0) red[wave] = acc;
    __syncthreads();

    if (t == 0)
        partials[bid] = red[0] + red[1] + red[2] + red[3];
}

__global__ __launch_bounds__(256) void probsnet_reduce(
    const float* __restrict__ partials, float* __restrict__ out)
{
    const int t = threadIdx.x;
    float acc = 0.0f;
    #pragma unroll
    for (int k = 0; k < BLOCKS / 256; ++k)   // 7 partials per thread
        acc += partials[t + k * 256];

    #pragma unroll
    for (int off = 32; off > 0; off >>= 1)
        acc += __shfl_down(acc, off, 64);

    __shared__ float red[4];
    const int wave = t >> 6;
    const int lane = t & 63;
    if (lane == 0) red[wave] = acc;
    __syncthreads();

    if (t == 0)
        out[0] = (red[0] + red[1] + red[2] + red[3]) * 0.2f;
}

extern "C" void kernel_launch(void* const* d_in, const int* in_sizes, int n_in,
                              void* d_out, int out_size, void* d_ws, size_t ws_size,
                              hipStream_t stream) {
    // setup_inputs order:
    // 0=BEV(1) 1=ST0 2=Weight0 3=ST1 4=Weight1 5=Problem(int,unused)
    // 6..10=probs0..probs4(4) 11=pBEV(1) 12=pB(1)
    const float* BEV    = (const float*)d_in[0];
    const float* ST0    = (const float*)d_in[1];
    const float* W0     = (const float*)d_in[2];
    const float* ST1    = (const float*)d_in[3];
    const float* W1     = (const float*)d_in[4];
    const float* probs0 = (const float*)d_in[6];
    const float* probs1 = (const float*)d_in[7];
    const float* probs2 = (const float*)d_in[8];
    const float* probs3 = (const float*)d_in[9];
    const float* probs4 = (const float*)d_in[10];
    const float* pBEV   = (const float*)d_in[11];
    const float* pB     = (const float*)d_in[12];

    float* partials = (float*)d_ws;          // 1792 floats = 7 KB of scratch
    float* out      = (float*)d_out;

    probsnet_main<<<BLOCKS, 256, 0, stream>>>(
        BEV, ST0, W0, ST1, W1,
        probs0, probs1, probs2, probs3, probs4,
        pBEV, pB, partials);

    probsnet_reduce<<<1, 256, 0, stream>>>(partials, out);
}

// Round 4
// 201.994 us; speedup vs baseline: 1.1070x; 1.0019x over previous
//
#include <hip/hip_runtime.h>
#include <hip/hip_bf16.h>

// ProbsNet: out = mean over 5 of [p_m @ tmp_{0 or 1}]
//   tmp_t[i] = sum_d sigmoid(pB*(pBEV*BEV + ST_t[i,d])) * W_t[i,d]
// R3 post-mortem: latency/tail-bound (occ 46%, VGPR 32, 2.67 TB/s effective).
// R4: 28 blocks/CU deep queue, sched_barrier-pinned load cluster,
//     rcp+exp2 fast sigmoid, dual-row accumulators (no LDS weight stage).

#define D_DIM         131072
#define N_ROWS        84
#define ROW_F4        (D_DIM / 4)             // 32768 float4 per row
#define TENSOR_F4     (N_ROWS * ROW_F4)       // 2752512 float4 per tensor
#define F4_PER_BLOCK  768
#define T0_BLOCKS     (TENSOR_F4 / F4_PER_BLOCK)   // 3584 (exact)
#define BLOCKS        (2 * T0_BLOCKS)              // 7168 = 28 blocks/CU
#define F4_PER_THREAD 3

// entry t of calc_probs(logits): i=t/21; r=t%21
//   r==0 -> p_i ; else r-=1, j=r/5, s=r%5: s==0 -> p_i*p_j else p_i*p_j*p_{s-1}
__device__ inline float prob_entry(const float* __restrict__ logits, int t) {
    float l0 = logits[0], l1 = logits[1], l2 = logits[2], l3 = logits[3];
    float m  = fmaxf(fmaxf(l0, l1), fmaxf(l2, l3));
    float e0 = __expf(l0 - m), e1 = __expf(l1 - m);
    float e2 = __expf(l2 - m), e3 = __expf(l3 - m);
    float inv = 1.0f / (e0 + e1 + e2 + e3);
    float p[4] = {e0 * inv, e1 * inv, e2 * inv, e3 * inv};
    int i = t / 21;
    int r = t - i * 21;
    if (r == 0) return p[i];
    r -= 1;
    int j = r / 5;
    int s = r - j * 5;
    float v = p[i] * p[j];
    return (s == 0) ? v : v * p[s - 1];
}

// w * sigmoid(pb*(bev+s)) = w * rcp(1 + exp2(a*s + a*bev)), a = -pb*log2(e)
__device__ inline float sigdot(float w, float s, float a, float ab) {
    float e = __builtin_amdgcn_exp2f(fmaf(a, s, ab));
    return w * __builtin_amdgcn_rcpf(1.0f + e);
}

__global__ __launch_bounds__(256, 4) void probsnet_main(
    const float* __restrict__ BEV,
    const float* __restrict__ ST0, const float* __restrict__ W0,
    const float* __restrict__ ST1, const float* __restrict__ W1,
    const float* __restrict__ probs0, const float* __restrict__ probs1,
    const float* __restrict__ probs2, const float* __restrict__ probs3,
    const float* __restrict__ probs4,
    const float* __restrict__ pBEV, const float* __restrict__ pB,
    float* __restrict__ partials)
{
    const int bid    = blockIdx.x;
    const int t      = threadIdx.x;
    const int tensor = (bid >= T0_BLOCKS) ? 1 : 0;
    const int fb     = (bid - tensor * T0_BLOCKS) * F4_PER_BLOCK;

    const float pb  = pB[0];
    const float bev = pBEV[0] * BEV[0];
    const float a   = -pb * 1.4426950408889634f;   // -pb*log2(e)
    const float ab  = a * bev;

    const float4* __restrict__ stp =
        (const float4*)(tensor ? ST1 : ST0) + fb + t;
    const float4* __restrict__ wpp =
        (const float4*)(tensor ? W1 : W0) + fb + t;

    // Issue all 6 loads, then pin them above the compute with a sched barrier
    // (R2/R3: without this the compiler sinks loads to uses -> 2 in flight).
    float4 sv[F4_PER_THREAD], wv[F4_PER_THREAD];
    #pragma unroll
    for (int k = 0; k < F4_PER_THREAD; ++k) {
        sv[k] = stp[k * 256];
        wv[k] = wpp[k * 256];
    }
    __builtin_amdgcn_sched_barrier(0);

    // Block spans at most 2 rows (768 < 32768). Split into two unweighted
    // accumulators; thread 0 applies softmax-expansion weights at the end.
    const int row_lo = fb >> 15;
    const int row_hi = (fb + F4_PER_BLOCK - 1) >> 15;
    const int rb     = (row_hi > row_lo) ? (row_hi << 15) : 0x7FFFFFFF;

    float acc_lo = 0.0f, acc_hi = 0.0f;
    #pragma unroll
    for (int k = 0; k < F4_PER_THREAD; ++k) {
        float c;
        c  = sigdot(wv[k].x, sv[k].x, a, ab);
        c += sigdot(wv[k].y, sv[k].y, a, ab);
        c += sigdot(wv[k].z, sv[k].z, a, ab);
        c += sigdot(wv[k].w, sv[k].w, a, ab);
        const bool hi = (fb + t + k * 256) >= rb;
        acc_lo += hi ? 0.0f : c;
        acc_hi += hi ? c : 0.0f;
    }

    // wave64 shuffle reduction of both accumulators
    #pragma unroll
    for (int off = 32; off > 0; off >>= 1) {
        acc_lo += __shfl_down(acc_lo, off, 64);
        acc_hi += __shfl_down(acc_hi, off, 64);
    }

    __shared__ float red_lo[4], red_hi[4];
    const int wave = t >> 6;
    const int lane = t & 63;
    if (lane == 0) { red_lo[wave] = acc_lo; red_hi[wave] = acc_hi; }
    __syncthreads();

    if (t == 0) {
        const float S_lo = red_lo[0] + red_lo[1] + red_lo[2] + red_lo[3];
        const float S_hi = red_hi[0] + red_hi[1] + red_hi[2] + red_hi[3];
        float w_lo, w_hi = 0.0f;
        if (tensor == 0) {
            w_lo = prob_entry(probs0, row_lo);
            if (row_hi > row_lo) w_hi = prob_entry(probs0, row_hi);
        } else {
            w_lo = prob_entry(probs1, row_lo) + prob_entry(probs2, row_lo)
                 + prob_entry(probs3, row_lo) + prob_entry(probs4, row_lo);
            if (row_hi > row_lo)
                w_hi = prob_entry(probs1, row_hi) + prob_entry(probs2, row_hi)
                     + prob_entry(probs3, row_hi) + prob_entry(probs4, row_hi);
        }
        partials[bid] = w_lo * S_lo + w_hi * S_hi;
    }
}

__global__ __launch_bounds__(256) void probsnet_reduce(
    const float* __restrict__ partials, float* __restrict__ out)
{
    const int t = threadIdx.x;
    float acc = 0.0f;
    #pragma unroll
    for (int k = 0; k < BLOCKS / 256; ++k)   // 28 partials per thread
        acc += partials[t + k * 256];

    #pragma unroll
    for (int off = 32; off > 0; off >>= 1)
        acc += __shfl_down(acc, off, 64);

    __shared__ float red[4];
    const int wave = t >> 6;
    const int lane = t & 63;
    if (lane == 0) red[wave] = acc;
    __syncthreads();

    if (t == 0)
        out[0] = (red[0] + red[1] + red[2] + red[3]) * 0.2f;
}

extern "C" void kernel_launch(void* const* d_in, const int* in_sizes, int n_in,
                              void* d_out, int out_size, void* d_ws, size_t ws_size,
                              hipStream_t stream) {
    // setup_inputs order:
    // 0=BEV(1) 1=ST0 2=Weight0 3=ST1 4=Weight1 5=Problem(int,unused)
    // 6..10=probs0..probs4(4) 11=pBEV(1) 12=pB(1)
    const float* BEV    = (const float*)d_in[0];
    const float* ST0    = (const float*)d_in[1];
    const float* W0     = (const float*)d_in[2];
    const float* ST1    = (const float*)d_in[3];
    const float* W1     = (const float*)d_in[4];
    const float* probs0 = (const float*)d_in[6];
    const float* probs1 = (const float*)d_in[7];
    const float* probs2 = (const float*)d_in[8];
    const float* probs3 = (const float*)d_in[9];
    const float* probs4 = (const float*)d_in[10];
    const float* pBEV   = (const float*)d_in[11];
    const float* pB     = (const float*)d_in[12];

    float* partials = (float*)d_ws;          // 7168 floats = 28 KB scratch
    float* out      = (float*)d_out;

    probsnet_main<<<BLOCKS, 256, 0, stream>>>(
        BEV, ST0, W0, ST1, W1,
        probs0, probs1, probs2, probs3, probs4,
        pBEV, pB, partials);

    probsnet_reduce<<<1, 256, 0, stream>>>(partials, out);
}

// Round 5
// 199.253 us; speedup vs baseline: 1.1222x; 1.0138x over previous
//
#include <hip/hip_runtime.h>
#include <hip/hip_bf16.h>

// ProbsNet: out = mean over 5 of [p_m @ tmp_{0 or 1}]
//   tmp_t[i] = sum_d sigmoid(pB*(pBEV*BEV + ST_t[i,d])) * W_t[i,d]
// R2-R4 post-mortem: compiler register-minimizes (VGPR 20-32) and sinks
// loads to uses -> ~2 loads in flight/wave -> latency-bound plateau ~62us.
// R5: loads + s_waitcnt fused in ONE volatile asm block -> compiler cannot
// sink/split; 8 x 16B guaranteed outstanding per lane (8KB/wave).

#define D_DIM         131072
#define N_ROWS        84
#define ROW_F4        (D_DIM / 4)                   // 32768 float4 per row
#define TENSOR_F4     (N_ROWS * ROW_F4)             // 2752512 float4 per tensor
#define F4_PER_BLOCK  1024                          // divides ROW_F4 -> 1 row/block
#define T0_BLOCKS     (TENSOR_F4 / F4_PER_BLOCK)    // 2688
#define BLOCKS        (2 * T0_BLOCKS)               // 5376 = exactly 21 blocks/CU

typedef float f32x4 __attribute__((ext_vector_type(4)));

// entry t of calc_probs(logits): i=t/21; r=t%21
//   r==0 -> p_i ; else r-=1, j=r/5, s=r%5: s==0 -> p_i*p_j else p_i*p_j*p_{s-1}
__device__ inline float prob_entry(const float* __restrict__ logits, int t) {
    float l0 = logits[0], l1 = logits[1], l2 = logits[2], l3 = logits[3];
    float m  = fmaxf(fmaxf(l0, l1), fmaxf(l2, l3));
    float e0 = __expf(l0 - m), e1 = __expf(l1 - m);
    float e2 = __expf(l2 - m), e3 = __expf(l3 - m);
    float inv = 1.0f / (e0 + e1 + e2 + e3);
    float p[4] = {e0 * inv, e1 * inv, e2 * inv, e3 * inv};
    int i = t / 21;
    int r = t - i * 21;
    if (r == 0) return p[i];
    r -= 1;
    int j = r / 5;
    int s = r - j * 5;
    float v = p[i] * p[j];
    return (s == 0) ? v : v * p[s - 1];
}

// w * sigmoid(pb*(bev+s)) = w * rcp(1 + exp2(a*s + ab)), a = -pb*log2(e)
__device__ inline float sigdot(float w, float s, float a, float ab) {
    float e = __builtin_amdgcn_exp2f(fmaf(a, s, ab));
    return w * __builtin_amdgcn_rcpf(1.0f + e);
}

__global__ __launch_bounds__(256, 4) void probsnet_main(
    const float* __restrict__ BEV,
    const float* __restrict__ ST0, const float* __restrict__ W0,
    const float* __restrict__ ST1, const float* __restrict__ W1,
    const float* __restrict__ probs0, const float* __restrict__ probs1,
    const float* __restrict__ probs2, const float* __restrict__ probs3,
    const float* __restrict__ probs4,
    const float* __restrict__ pBEV, const float* __restrict__ pB,
    float* __restrict__ partials)
{
    const int bid    = blockIdx.x;
    const int t      = threadIdx.x;
    const int tensor = (bid >= T0_BLOCKS) ? 1 : 0;
    const int fb     = (bid - tensor * T0_BLOCKS) * F4_PER_BLOCK;
    const int row    = fb >> 15;                    // single row per block

    const float pb  = pB[0];
    const float bev = pBEV[0] * BEV[0];
    const float a   = -pb * 1.4426950408889634f;    // -pb*log2(e)
    const float ab  = a * bev;

    const f32x4* sp = (const f32x4*)(tensor ? ST1 : ST0) + fb + t;
    const f32x4* wp = (const f32x4*)(tensor ? W1  : W0 ) + fb + t;

    // Single volatile asm block: 8 loads + waitcnt are indivisible — the
    // compiler can neither sink the loads to uses nor hoist uses above the
    // wait. Guarantees 8 x 16B outstanding per lane.
    f32x4 s0, s1, s2, s3, w0, w1, w2, w3;
    asm volatile(
        "global_load_dwordx4 %0, %8, off\n\t"
        "global_load_dwordx4 %4, %12, off\n\t"
        "global_load_dwordx4 %1, %9, off\n\t"
        "global_load_dwordx4 %5, %13, off\n\t"
        "global_load_dwordx4 %2, %10, off\n\t"
        "global_load_dwordx4 %6, %14, off\n\t"
        "global_load_dwordx4 %3, %11, off\n\t"
        "global_load_dwordx4 %7, %15, off\n\t"
        "s_waitcnt vmcnt(0)"
        : "=&v"(s0), "=&v"(s1), "=&v"(s2), "=&v"(s3),
          "=&v"(w0), "=&v"(w1), "=&v"(w2), "=&v"(w3)
        : "v"(sp), "v"(sp + 256), "v"(sp + 512), "v"(sp + 768),
          "v"(wp), "v"(wp + 256), "v"(wp + 512), "v"(wp + 768));

    float acc = 0.0f;
    acc += sigdot(w0[0], s0[0], a, ab); acc += sigdot(w0[1], s0[1], a, ab);
    acc += sigdot(w0[2], s0[2], a, ab); acc += sigdot(w0[3], s0[3], a, ab);
    acc += sigdot(w1[0], s1[0], a, ab); acc += sigdot(w1[1], s1[1], a, ab);
    acc += sigdot(w1[2], s1[2], a, ab); acc += sigdot(w1[3], s1[3], a, ab);
    acc += sigdot(w2[0], s2[0], a, ab); acc += sigdot(w2[1], s2[1], a, ab);
    acc += sigdot(w2[2], s2[2], a, ab); acc += sigdot(w2[3], s2[3], a, ab);
    acc += sigdot(w3[0], s3[0], a, ab); acc += sigdot(w3[1], s3[1], a, ab);
    acc += sigdot(w3[2], s3[2], a, ab); acc += sigdot(w3[3], s3[3], a, ab);

    // wave64 shuffle reduction
    #pragma unroll
    for (int off = 32; off > 0; off >>= 1)
        acc += __shfl_down(acc, off, 64);

    __shared__ float red[4];
    const int wave = t >> 6;
    const int lane = t & 63;
    if (lane == 0) red[wave] = acc;
    __syncthreads();

    if (t == 0) {
        const float S = red[0] + red[1] + red[2] + red[3];
        float pw;
        if (tensor == 0) {
            pw = prob_entry(probs0, row);
        } else {
            pw = prob_entry(probs1, row) + prob_entry(probs2, row)
               + prob_entry(probs3, row) + prob_entry(probs4, row);
        }
        partials[bid] = pw * S;
    }
}

__global__ __launch_bounds__(256) void probsnet_reduce(
    const float* __restrict__ partials, float* __restrict__ out)
{
    const int t = threadIdx.x;
    float acc = 0.0f;
    #pragma unroll
    for (int k = 0; k < BLOCKS / 256; ++k)   // 21 partials per thread
        acc += partials[t + k * 256];

    #pragma unroll
    for (int off = 32; off > 0; off >>= 1)
        acc += __shfl_down(acc, off, 64);

    __shared__ float red[4];
    const int wave = t >> 6;
    const int lane = t & 63;
    if (lane == 0) red[wave] = acc;
    __syncthreads();

    if (t == 0)
        out[0] = (red[0] + red[1] + red[2] + red[3]) * 0.2f;
}

extern "C" void kernel_launch(void* const* d_in, const int* in_sizes, int n_in,
                              void* d_out, int out_size, void* d_ws, size_t ws_size,
                              hipStream_t stream) {
    // setup_inputs order:
    // 0=BEV(1) 1=ST0 2=Weight0 3=ST1 4=Weight1 5=Problem(int,unused)
    // 6..10=probs0..probs4(4) 11=pBEV(1) 12=pB(1)
    const float* BEV    = (const float*)d_in[0];
    const float* ST0    = (const float*)d_in[1];
    const float* W0     = (const float*)d_in[2];
    const float* ST1    = (const float*)d_in[3];
    const float* W1     = (const float*)d_in[4];
    const float* probs0 = (const float*)d_in[6];
    const float* probs1 = (const float*)d_in[7];
    const float* probs2 = (const float*)d_in[8];
    const float* probs3 = (const float*)d_in[9];
    const float* probs4 = (const float*)d_in[10];
    const float* pBEV   = (const float*)d_in[11];
    const float* pB     = (const float*)d_in[12];

    float* partials = (float*)d_ws;          // 5376 floats = 21 KB scratch
    float* out      = (float*)d_out;

    probsnet_main<<<BLOCKS, 256, 0, stream>>>(
        BEV, ST0, W0, ST1, W1,
        probs0, probs1, probs2, probs3, probs4,
        pBEV, pB, partials);

    probsnet_reduce<<<1, 256, 0, stream>>>(partials, out);
}